// Round 3
// baseline (1831.452 us; speedup 1.0000x reference)
//
#include <hip/hip_runtime.h>
#include <hip/hip_bf16.h>

#define NN 64
#define CC 128
#define TT 64
#define VV 25
#define VP 32   // padded V

// LDS layout (float offsets)
#define OFF_ZB   0        // zbuf[2][VP*CC] = 2*4096
#define OFF_XA   8192     // xa[CC*VP]  (normal layout [c][v])
#define OFF_XB   12288    // xb[4096]   (T [v][c] or N [c][v] depending on phase)
#define OFF_FT   16384    // fT[6][VV*CC] = 6*3200   (transposed [v][c])
#define OFF_AT   35584    // At[VP*VP]: At[u][v] = A[v][u], zero-padded v>=25
#define OFF_ASUM 36608    // Asum[VP]
#define LDS_FLOATS 36640  // 146,560 bytes

typedef float f4 __attribute__((ext_vector_type(4)));

__device__ __forceinline__ f4 splat4(float s) { f4 r = {s, s, s, s}; return r; }

// ---------------- A-mix: y[c][v] = sum_u A[v][u] x[u][c]  (+ pe_c * Asum[v]) ----------------
// input transposed xT[u][c], output normal yN[c][v]. Thread tile: 4c x 4v.
__device__ __forceinline__ void amix(const float* __restrict__ xT,
                                     float* __restrict__ yN,
                                     const float* __restrict__ At,
                                     const float* __restrict__ Asum,
                                     const float* __restrict__ pe, int t3, // 3*t, or -1 for no pe
                                     int r0, int v0)
{
    f4 acc[4];
    if (t3 >= 0) {
        f4 as = *(const f4*)&Asum[v0];
        #pragma unroll
        for (int i = 0; i < 4; ++i) {
            float p = pe[(r0 + i) * 192 + t3];
            acc[i] = p * as;
        }
    } else {
        #pragma unroll
        for (int i = 0; i < 4; ++i) acc[i] = splat4(0.f);
    }
    #pragma unroll 5
    for (int u = 0; u < VV; ++u) {
        f4 xq = *(const f4*)&xT[u * CC + r0];
        f4 aq = *(const f4*)&At[u * VP + v0];
        #pragma unroll
        for (int i = 0; i < 4; ++i) acc[i] += xq[i] * aq;
    }
    #pragma unroll
    for (int i = 0; i < 4; ++i)
        *(f4*)&yN[(r0 + i) * VP + v0] = acc[i];
}

// ---------------- W-mix: out[o][v] = sum_c W[o][c] x[c][v] + b[o] ----------------
// input normal xN[c][v]. MODE 0: out transposed [v][o] + tanh (feeds A-mix)
//                        MODE 1: out normal [o][v] + tanh (feeds Wp)
//                        MODE 2: out transposed [v][o], no tanh, v<25 only (f ring slot)
template <int MODE>
__device__ __forceinline__ void wmix(const float* __restrict__ xN,
                                     float* __restrict__ dst,
                                     const float* __restrict__ W,
                                     const float* __restrict__ B,
                                     int r0, int v0)
{
    f4 acc[4];
    f4 bb = *(const f4*)&B[r0];
    #pragma unroll
    for (int i = 0; i < 4; ++i) acc[i] = splat4(bb[i]);

    #pragma unroll 2
    for (int cq = 0; cq < 32; ++cq) {
        f4 w[4], xq[4];
        #pragma unroll
        for (int i = 0; i < 4; ++i) w[i] = *(const f4*)&W[(r0 + i) * CC + cq * 4];
        #pragma unroll
        for (int k = 0; k < 4; ++k) xq[k] = *(const f4*)&xN[(cq * 4 + k) * VP + v0];
        #pragma unroll
        for (int i = 0; i < 4; ++i)
            #pragma unroll
            for (int k = 0; k < 4; ++k)
                acc[i] += w[i][k] * xq[k];
    }

    if (MODE == 0) {
        #pragma unroll
        for (int j = 0; j < 4; ++j) {
            f4 o = { tanhf(acc[0][j]), tanhf(acc[1][j]), tanhf(acc[2][j]), tanhf(acc[3][j]) };
            *(f4*)&dst[(v0 + j) * CC + r0] = o;
        }
    } else if (MODE == 1) {
        #pragma unroll
        for (int i = 0; i < 4; ++i) {
            f4 o = { tanhf(acc[i][0]), tanhf(acc[i][1]), tanhf(acc[i][2]), tanhf(acc[i][3]) };
            *(f4*)&dst[(r0 + i) * VP + v0] = o;
        }
    } else {
        #pragma unroll
        for (int j = 0; j < 4; ++j) {
            if (v0 + j < VV) {
                f4 o = { acc[0][j], acc[1][j], acc[2][j], acc[3][j] };
                *(f4*)&dst[(v0 + j) * CC + r0] = o;
            }
        }
    }
}

// ---------------- one ODE evaluation: zT (transposed [v][c]) -> fdst (transposed [v][c]) ----
// Every phase is barrier-separated on BOTH sides (incl. a trailing barrier), so no
// two phases ever share a barrier interval with code outside ode_step.
__device__ __forceinline__ void ode_step(int t, const float* __restrict__ zT,
                                         float* __restrict__ fdst,
                                         float* xa, float* xb,
                                         const float* At, const float* Asum,
                                         const float* __restrict__ pe,
                                         const float* __restrict__ W1, const float* __restrict__ b1,
                                         const float* __restrict__ W2, const float* __restrict__ b2,
                                         const float* __restrict__ W3, const float* __restrict__ b3,
                                         const float* __restrict__ Wp, const float* __restrict__ bp,
                                         int r0, int v0)
{
    amix(zT, xa, At, Asum, pe, 3 * t, r0, v0);
    __syncthreads();
    wmix<0>(xa, xb, W1, b1, r0, v0);   // -> T
    __syncthreads();
    amix(xb, xa, At, Asum, nullptr, -1, r0, v0);
    __syncthreads();
    wmix<0>(xa, xb, W2, b2, r0, v0);   // -> T
    __syncthreads();
    amix(xb, xa, At, Asum, nullptr, -1, r0, v0);
    __syncthreads();
    wmix<1>(xa, xb, W3, b3, r0, v0);   // -> N (feeds Wp)
    __syncthreads();
    wmix<2>(xb, fdst, Wp, bp, r0, v0); // -> f ring slot (T), no tanh
    __syncthreads();
}

__global__ __launch_bounds__(256, 1)
void infogcn_kernel(const float* __restrict__ h, const float* __restrict__ mr,
                    const float* __restrict__ A, const float* __restrict__ pe,
                    const float* __restrict__ W1, const float* __restrict__ b1,
                    const float* __restrict__ W2, const float* __restrict__ b2,
                    const float* __restrict__ W3, const float* __restrict__ b3,
                    const float* __restrict__ Wp, const float* __restrict__ bp,
                    float* __restrict__ out)
{
    extern __shared__ float lds[];
    float* zb   = lds + OFF_ZB;
    float* xa   = lds + OFF_XA;
    float* xb   = lds + OFF_XB;
    float* fT   = lds + OFF_FT;
    float* At   = lds + OFF_AT;
    float* Asum = lds + OFF_ASUM;

    const int tid = threadIdx.x;
    const int n = blockIdx.x;
    const float* hn = h + (size_t)n * (CC * TT * VV);
    float* on = out + (size_t)n * (CC * TT * VV);
    const int r0 = (tid >> 3) * 4;   // row-tile base (c or o)
    const int v0 = (tid & 7) * 4;    // v-tile base

    // ---- launch-state invariance: zero ALL of LDS before anything reads it ----
    for (int idx = tid; idx < LDS_FLOATS; idx += 256) lds[idx] = 0.f;
    __syncthreads();

    // ---- init At (transposed, zero-padded) and Asum ----
    for (int idx = tid; idx < VP * VP; idx += 256) {
        int u = idx >> 5, v = idx & 31;
        At[idx] = (u < VV && v < VV) ? A[v * VV + u] : 0.f;
    }
    if (tid < VP) {
        float s = 0.f;
        if (tid < VV)
            for (int u = 0; u < VV; ++u) s += A[tid * VV + u];
        Asum[tid] = s;
    }

    // ---- out[:, :, 0:6, :] = h[:, :, 0:6, :]  (150 contiguous floats per channel) ----
    for (int idx = tid; idx < CC * 6 * VV; idx += 256) {
        int c = idx / 150;
        int r = idx - c * 150;
        on[c * (TT * VV) + r] = hn[c * (TT * VV) + r];
    }
    __syncthreads();

    // ---- initial 6 odes: fT[i] = ode(i, h[:,:,i,:]) ----
    for (int i = 0; i < 6; ++i) {
        for (int idx = tid; idx < CC * VP; idx += 256) {
            int c = idx >> 5, v = idx & 31;
            zb[v * CC + c] = (v < VV) ? hn[c * (TT * VV) + i * VV + v] : 0.f;
        }
        __syncthreads();
        ode_step(i, zb, fT + i * 3200, xa, xb, At, Asum, pe,
                 W1, b1, W2, b2, W3, b3, Wp, bp, r0, v0);
        __syncthreads();
    }

    // ---- z_cand = h[:,:,5,:] ----
    for (int idx = tid; idx < CC * VP; idx += 256) {
        int c = idx >> 5, v = idx & 31;
        zb[v * CC + c] = (v < VV) ? hn[c * (TT * VV) + 5 * VV + v] : 0.f;
    }
    __syncthreads();

    const float coef[6] = { 4277.f / 1440.f, -7923.f / 1440.f, 9982.f / 1440.f,
                            -7298.f / 1440.f, 2877.f / 1440.f, -475.f / 1440.f };
    int cur = 0, head = 5;

    for (int t = 5; t < TT - 1; ++t) {
        float* zt = zb + cur * 4096;
        float* zn = zb + (1 - cur) * 4096;
        bool m = mr[(t - 5) * NN + n] < 0.8f;
        if (!m) {  // z_t = h_t (uniform branch across block)
            for (int idx = tid; idx < CC * VP; idx += 256) {
                int c = idx >> 5, v = idx & 31;
                zt[v * CC + c] = (v < VV) ? hn[c * (TT * VV) + t * VV + v] : 0.f;
            }
        }
        __syncthreads();

        // z_next = z_t + sum_k coef[k] * f_{t-k};  store to out[:, :, t+1, :] and zn
        for (int idx = tid; idx < VV * 32; idx += 256) {
            int v = idx >> 5;
            int cq = (idx & 31) * 4;
            f4 r = *(const f4*)&zt[v * CC + cq];
            #pragma unroll
            for (int k = 0; k < 6; ++k) {
                int s = head - k; if (s < 0) s += 6;
                f4 f = *(const f4*)&fT[s * 3200 + v * CC + cq];
                r += coef[k] * f;
            }
            *(f4*)&zn[v * CC + cq] = r;
            #pragma unroll
            for (int i = 0; i < 4; ++i)
                on[(cq + i) * (TT * VV) + (t + 1) * VV + v] = r[i];
        }
        __syncthreads();   // z-update fully done before ode_step touches anything

        // f_t = ode(t, z_t) into the oldest ring slot
        int slot = head + 1; if (slot >= 6) slot = 0;
        ode_step(t, zt, fT + slot * 3200, xa, xb, At, Asum, pe,
                 W1, b1, W2, b2, W3, b3, Wp, bp, r0, v0);
        __syncthreads();
        head = slot;
        cur ^= 1;
    }
}

extern "C" void kernel_launch(void* const* d_in, const int* in_sizes, int n_in,
                              void* d_out, int out_size, void* d_ws, size_t ws_size,
                              hipStream_t stream) {
    const float* h  = (const float*)d_in[0];
    const float* mr = (const float*)d_in[1];
    const float* A  = (const float*)d_in[2];
    const float* pe = (const float*)d_in[3];
    const float* W1 = (const float*)d_in[4];
    const float* b1 = (const float*)d_in[5];
    const float* W2 = (const float*)d_in[6];
    const float* b2 = (const float*)d_in[7];
    const float* W3 = (const float*)d_in[8];
    const float* b3 = (const float*)d_in[9];
    const float* Wp = (const float*)d_in[10];
    const float* bp = (const float*)d_in[11];
    float* out = (float*)d_out;

    const size_t ldsB = LDS_FLOATS * sizeof(float);
    (void)hipFuncSetAttribute((const void*)infogcn_kernel,
                              hipFuncAttributeMaxDynamicSharedMemorySize, (int)ldsB);
    infogcn_kernel<<<dim3(NN), dim3(256), ldsB, stream>>>(
        h, mr, A, pe, W1, b1, W2, b2, W3, b3, Wp, bp, out);
}

// Round 4
// 758.125 us; speedup vs baseline: 2.4158x; 2.4158x over previous
//
#include <hip/hip_runtime.h>

#define NN 64
#define CC 128
#define TT 64
#define VVJ 25

typedef __attribute__((ext_vector_type(4))) float f4;
typedef __attribute__((ext_vector_type(8))) short bh8;  // 8 bf16 (4 VGPR) MFMA frag
typedef __attribute__((ext_vector_type(4))) short bh4;  // 4 bf16 (b64 LDS store)

// ---- LDS byte offsets ----
// zf  : float[25][128]          12800 B   fp32 z state, [v][c]
// fT  : float[6][25][132]       79200 B   fp32 f ring,  [slot][v][c] stride 132 (bank spread)
// xUh/xUl : bf16[128][32]        8192 B each   x in [c][u] (u contig), XOR-swizzled
// xVh/xVl : bf16[32][128]        8192 B each   x in [v][c] (c contig), XOR-swizzled
#define ZF_OFF   0
#define FT_OFF   12800
#define XUH_OFF  92000
#define XUL_OFF  100192
#define XVH_OFF  108384
#define XVL_OFF  116576
#define LDS_BYTES 124768

__device__ __forceinline__ f4 mfma16(bh8 a, bh8 b, f4 c) {
    return __builtin_amdgcn_mfma_f32_16x16x32_bf16(a, b, c, 0, 0, 0);
}

__device__ __forceinline__ float fast_tanh(float x) {
    float e = __expf(2.f * x);           // v_mul + v_exp
    return 1.f - 2.f / (e + 1.f);        // saturates cleanly to +/-1 on overflow
}

__global__ __launch_bounds__(256, 1)
void infogcn_mfma(const float* __restrict__ h, const float* __restrict__ mr,
                  const float* __restrict__ A, const float* __restrict__ pe,
                  const float* __restrict__ W1, const float* __restrict__ b1,
                  const float* __restrict__ W2, const float* __restrict__ b2,
                  const float* __restrict__ W3, const float* __restrict__ b3,
                  const float* __restrict__ Wp, const float* __restrict__ bp,
                  float* __restrict__ out)
{
    extern __shared__ char lds[];
    float* zf = (float*)(lds + ZF_OFF);
    float* fT = (float*)(lds + FT_OFF);
    char* xUh = lds + XUH_OFF;  char* xUl = lds + XUL_OFF;
    char* xVh = lds + XVH_OFF;  char* xVl = lds + XVL_OFF;

    const int tid  = threadIdx.x;
    const int lane = tid & 63;
    const int w    = tid >> 6;       // wave id 0..3 (one per SIMD)
    const int col  = lane & 15;
    const int kg   = lane >> 4;      // 0..3
    const int n    = blockIdx.x;
    const float* hn = h   + (size_t)n * (CC * TT * VVJ);
    float*       on = out + (size_t)n * (CC * TT * VVJ);

    // ================= resident W fragments (bf16 hi/lo), loop-invariant =================
    // wmix: Q[v,o] = sum_c X[v,c] * W[o,c].  B-operand = W^T: col o = 32w+16nt+col,
    // k c = 32ks + kg*8 + e  (contiguous 8 -> direct from row-major W).
    bh8 Wh[4][2][4], Wl[4][2][4];     // [mat][nt][ks]  -> 256 VGPRs
    float bias[4][2];
    {
        const float* Wm[4] = {W1, W2, W3, Wp};
        const float* Bm[4] = {b1, b2, b3, bp};
        #pragma unroll
        for (int mat = 0; mat < 4; ++mat) {
            #pragma unroll
            for (int nt = 0; nt < 2; ++nt) {
                int o = 32*w + 16*nt + col;
                bias[mat][nt] = Bm[mat][o];
                #pragma unroll
                for (int ks = 0; ks < 4; ++ks) {
                    int c0 = 32*ks + kg*8;
                    #pragma unroll
                    for (int e = 0; e < 8; ++e) {
                        float x = Wm[mat][o*CC + c0 + e];
                        unsigned xb = __float_as_uint(x);
                        Wh[mat][nt][ks][e] = (short)(xb >> 16);
                        float lo = x - __uint_as_float(xb & 0xffff0000u);
                        Wl[mat][nt][ks][e] = (short)(__float_as_uint(lo) >> 16);
                    }
                }
            }
        }
    }
    // amix: P[c,v] = sum_u Z[c,u] * At[u,v], At[u,v] = A[v,u] (zero-padded).
    // B-operand = At: col v = 16nt+col, k u = kg*8+e.
    bh8 Ath[2], Atl[2];
    float asum[2];
    #pragma unroll
    for (int nt = 0; nt < 2; ++nt) {
        int v = 16*nt + col;
        #pragma unroll
        for (int e = 0; e < 8; ++e) {
            int u = kg*8 + e;
            float x = (v < VVJ && u < VVJ) ? A[v*VVJ + u] : 0.f;
            unsigned xb = __float_as_uint(x);
            Ath[nt][e] = (short)(xb >> 16);
            float lo = x - __uint_as_float(xb & 0xffff0000u);
            Atl[nt][e] = (short)(__float_as_uint(lo) >> 16);
        }
        float s = 0.f;
        if (v < VVJ)
            for (int u = 0; u < VVJ; ++u) s += A[v*VVJ + u];
        asum[nt] = s;
    }

    // zero xU (0xAA poison would be NaN; NaN*0 = NaN in MFMA K-padding)
    for (int idx = tid; idx < 2048; idx += 256) {
        ((unsigned*)xUh)[idx] = 0u;
        ((unsigned*)xUl)[idx] = 0u;
    }
    // out[:, :, 0:6, :] = h[:, :, 0:6, :]
    for (int idx = tid; idx < CC*6*VVJ; idx += 256) {
        int c = idx / 150, r = idx - c*150;
        on[c*(TT*VVJ) + r] = hn[c*(TT*VVJ) + r];
    }
    __syncthreads();

    // ================= phase lambdas =================
    // amix: reads xU[c][u] as A-frag (row c = 32w+16m+col), B = At frags.
    // D: rows c0 = 32w+16m+kg*4 (+i), col v = 16nt+col.  Stores xV[v][c0..c0+3] b64.
    auto amix = [&](bool withPE, int t3) {
        #pragma unroll
        for (int m = 0; m < 2; ++m) {
            int cA = 32*w + 16*m + col;
            int bau = (cA*64 + kg*16) ^ ((cA&7)<<4);
            bh8 xh = *(bh8*)(xUh + bau);
            bh8 xl = *(bh8*)(xUl + bau);
            int c0 = 32*w + 16*m + kg*4;
            float pe4[4];
            if (withPE) {
                #pragma unroll
                for (int i = 0; i < 4; ++i) pe4[i] = pe[(c0+i)*192 + t3];
            }
            #pragma unroll
            for (int nt = 0; nt < 2; ++nt) {
                f4 acc;
                if (withPE) {
                    #pragma unroll
                    for (int i = 0; i < 4; ++i) acc[i] = pe4[i] * asum[nt];
                } else {
                    acc = (f4){0.f, 0.f, 0.f, 0.f};
                }
                acc = mfma16(xh, Ath[nt], acc);
                acc = mfma16(xh, Atl[nt], acc);
                acc = mfma16(xl, Ath[nt], acc);
                int v = 16*nt + col;
                bh4 h4, l4;
                #pragma unroll
                for (int i = 0; i < 4; ++i) {
                    unsigned xb = __float_as_uint(acc[i]);
                    h4[i] = (short)(xb >> 16);
                    float lo = acc[i] - __uint_as_float(xb & 0xffff0000u);
                    l4[i] = (short)(__float_as_uint(lo) >> 16);
                }
                int ba = (v*256 + c0*2) ^ ((v&7)<<4);
                *(bh4*)(xVh + ba) = h4;
                *(bh4*)(xVl + ba) = l4;
            }
        }
    };

    // wmix core: A-frags from xV (row v = 16m+col, k c = 32ks+kg*8), B = W frags.
    auto wmix_core = [&](const bh8 (&wh)[2][4], const bh8 (&wl)[2][4], f4 (&acc)[2][2]) {
        #pragma unroll
        for (int m = 0; m < 2; ++m) {
            int vA = 16*m + col;
            int sw = (vA&7) << 4;
            #pragma unroll
            for (int ks = 0; ks < 4; ++ks) {
                int ba = (vA*256 + ks*64 + kg*16) ^ sw;
                bh8 xh = *(bh8*)(xVh + ba);
                bh8 xl = *(bh8*)(xVl + ba);
                #pragma unroll
                for (int nt = 0; nt < 2; ++nt) {
                    acc[m][nt] = mfma16(xh, wh[nt][ks], acc[m][nt]);
                    acc[m][nt] = mfma16(xh, wl[nt][ks], acc[m][nt]);
                    acc[m][nt] = mfma16(xl, wh[nt][ks], acc[m][nt]);
                }
            }
        }
    };

    // gc store: tanh, hi/lo, -> xU[o][v0..v0+3] b64 (feeds next amix)
    auto gc_store = [&](const f4 (&acc)[2][2], float bo0, float bo1) {
        #pragma unroll
        for (int m = 0; m < 2; ++m) {
            int v0 = 16*m + kg*4;
            #pragma unroll
            for (int nt = 0; nt < 2; ++nt) {
                float bo = (nt == 0) ? bo0 : bo1;
                int o = 32*w + 16*nt + col;
                bh4 h4, l4;
                #pragma unroll
                for (int i = 0; i < 4; ++i) {
                    float y = fast_tanh(acc[m][nt][i] + bo);
                    unsigned xb = __float_as_uint(y);
                    h4[i] = (short)(xb >> 16);
                    float lo = y - __uint_as_float(xb & 0xffff0000u);
                    l4[i] = (short)(__float_as_uint(lo) >> 16);
                }
                int ba = (o*64 + v0*2) ^ ((o&7)<<4);
                *(bh4*)(xUh + ba) = h4;
                *(bh4*)(xUl + ba) = l4;
            }
        }
    };

    // gc3 store: tanh, hi/lo, -> xV[v][o] scalar (feeds Wp as A-operand)
    auto gc3_store = [&](const f4 (&acc)[2][2], float bo0, float bo1) {
        #pragma unroll
        for (int m = 0; m < 2; ++m) {
            #pragma unroll
            for (int nt = 0; nt < 2; ++nt) {
                float bo = (nt == 0) ? bo0 : bo1;
                int o = 32*w + 16*nt + col;
                #pragma unroll
                for (int i = 0; i < 4; ++i) {
                    int v = 16*m + kg*4 + i;
                    float y = fast_tanh(acc[m][nt][i] + bo);
                    unsigned xb = __float_as_uint(y);
                    float lo = y - __uint_as_float(xb & 0xffff0000u);
                    int ba = (v*256 + o*2) ^ ((v&7)<<4);
                    *(short*)(xVh + ba) = (short)(xb >> 16);
                    *(short*)(xVl + ba) = (short)(__float_as_uint(lo) >> 16);
                }
            }
        }
    };

    // Wp store: fp32 + bias -> fT ring slot (no tanh), rows v<25 only
    auto wp_store = [&](const f4 (&acc)[2][2], int slot) {
        #pragma unroll
        for (int m = 0; m < 2; ++m) {
            #pragma unroll
            for (int nt = 0; nt < 2; ++nt) {
                float bo = (nt == 0) ? bias[3][0] : bias[3][1];
                int o = 32*w + 16*nt + col;
                #pragma unroll
                for (int i = 0; i < 4; ++i) {
                    int v = 16*m + kg*4 + i;
                    if (v < VVJ)
                        fT[slot*3300 + v*132 + o] = acc[m][nt][i] + bo;
                }
            }
        }
    };

    auto ode = [&](int t, int slot) {
        // pre: zU (=z_t, bf16 hi/lo) in xU; barrier already done
        amix(true, 3*t);                 // xU -> xV   (+pe fold)
        __syncthreads();
        f4 acc[2][2];
        #pragma unroll
        for (int m = 0; m < 2; ++m)
            #pragma unroll
            for (int nt = 0; nt < 2; ++nt) acc[m][nt] = (f4){0.f,0.f,0.f,0.f};
        wmix_core(Wh[0], Wl[0], acc);
        gc_store(acc, bias[0][0], bias[0][1]);   // xV -> xU
        __syncthreads();
        amix(false, 0);
        __syncthreads();
        #pragma unroll
        for (int m = 0; m < 2; ++m)
            #pragma unroll
            for (int nt = 0; nt < 2; ++nt) acc[m][nt] = (f4){0.f,0.f,0.f,0.f};
        wmix_core(Wh[1], Wl[1], acc);
        gc_store(acc, bias[1][0], bias[1][1]);
        __syncthreads();
        amix(false, 0);
        __syncthreads();
        #pragma unroll
        for (int m = 0; m < 2; ++m)
            #pragma unroll
            for (int nt = 0; nt < 2; ++nt) acc[m][nt] = (f4){0.f,0.f,0.f,0.f};
        wmix_core(Wh[2], Wl[2], acc);    // reads xV
        __syncthreads();                 // all xV reads complete
        gc3_store(acc, bias[2][0], bias[2][1]);  // overwrite xV in [v][c] layout
        __syncthreads();
        #pragma unroll
        for (int m = 0; m < 2; ++m)
            #pragma unroll
            for (int nt = 0; nt < 2; ++nt) acc[m][nt] = (f4){0.f,0.f,0.f,0.f};
        wmix_core(Wh[3], Wl[3], acc);    // Wp reads xV
        wp_store(acc, slot);
        __syncthreads();
    };

    // ================= initial 6 odes: fT[i] = ode(i, h[:,:,i,:]) =================
    #pragma unroll 1
    for (int i = 0; i < 6; ++i) {
        for (int idx = tid; idx < 896; idx += 256) {   // 7 u-quads x 128 c
            int uq = idx >> 7, c = idx & 127;
            int u0 = uq * 4;
            bh4 h4, l4;
            #pragma unroll
            for (int j = 0; j < 4; ++j) {
                int u = u0 + j;
                float z = (u < VVJ) ? hn[c*1600 + i*25 + u] : 0.f;
                unsigned xb = __float_as_uint(z);
                h4[j] = (short)(xb >> 16);
                float lo = z - __uint_as_float(xb & 0xffff0000u);
                l4[j] = (short)(__float_as_uint(lo) >> 16);
            }
            int ba = (c*64 + u0*2) ^ ((c&7)<<4);
            *(bh4*)(xUh + ba) = h4;
            *(bh4*)(xUl + ba) = l4;
        }
        __syncthreads();
        ode(i, i);
    }

    // z_cand = h[:,:,5,:]  (fp32 state)
    for (int idx = tid; idx < 800; idx += 256) {
        int v = idx >> 5, cq = (idx & 31) * 4;
        f4 zq;
        #pragma unroll
        for (int i = 0; i < 4; ++i) zq[i] = hn[(cq+i)*1600 + 5*25 + v];
        *(f4*)&zf[v*CC + cq] = zq;
    }
    __syncthreads();

    const float coef[6] = { 4277.f/1440.f, -7923.f/1440.f, 9982.f/1440.f,
                            -7298.f/1440.f, 2877.f/1440.f, -475.f/1440.f };
    int head = 5;

    #pragma unroll 1
    for (int t = 5; t < TT-1; ++t) {
        bool msk = mr[(t-5)*NN + n] < 0.8f;      // block-uniform
        if (!msk) {                              // z_t = h_t
            for (int idx = tid; idx < 800; idx += 256) {
                int v = idx >> 5, cq = (idx & 31) * 4;
                #pragma unroll
                for (int i = 0; i < 4; ++i)
                    zf[v*CC + cq + i] = hn[(cq+i)*1600 + t*25 + v];
            }
        }
        __syncthreads();
        // zU (bf16 hi/lo snapshot of z_t) for the ode
        for (int idx = tid; idx < 896; idx += 256) {
            int uq = idx >> 7, c = idx & 127;
            int u0 = uq * 4;
            bh4 h4, l4;
            #pragma unroll
            for (int j = 0; j < 4; ++j) {
                int u = u0 + j;
                float z = (u < VVJ) ? zf[u*CC + c] : 0.f;
                unsigned xb = __float_as_uint(z);
                h4[j] = (short)(xb >> 16);
                float lo = z - __uint_as_float(xb & 0xffff0000u);
                l4[j] = (short)(__float_as_uint(lo) >> 16);
            }
            int ba = (c*64 + u0*2) ^ ((c&7)<<4);
            *(bh4*)(xUh + ba) = h4;
            *(bh4*)(xUl + ba) = l4;
        }
        __syncthreads();
        // z_next = z_t + sum_k coef[k]*f_{t-1-k}; store out[:, :, t+1, :]; zf <- z_next
        for (int idx = tid; idx < 800; idx += 256) {
            int v = idx >> 5, cq = (idx & 31) * 4;
            f4 r = *(f4*)&zf[v*CC + cq];
            #pragma unroll
            for (int k = 0; k < 6; ++k) {
                int s = head - k; if (s < 0) s += 6;
                f4 fq = *(f4*)&fT[s*3300 + v*132 + cq];
                r += coef[k] * fq;
            }
            *(f4*)&zf[v*CC + cq] = r;
            #pragma unroll
            for (int i = 0; i < 4; ++i)
                on[(cq+i)*1600 + (t+1)*25 + v] = r[i];
        }
        // f_t = ode(t, z_t) into oldest slot (skip at final step: f_62 unused)
        if (t < TT-2) {
            int slot = head + 1; if (slot >= 6) slot = 0;
            ode(t, slot);                        // amix1 shares interval with z-update
            head = slot;
        } else {
            __syncthreads();
        }
    }
}

extern "C" void kernel_launch(void* const* d_in, const int* in_sizes, int n_in,
                              void* d_out, int out_size, void* d_ws, size_t ws_size,
                              hipStream_t stream) {
    const float* h  = (const float*)d_in[0];
    const float* mr = (const float*)d_in[1];
    const float* A  = (const float*)d_in[2];
    const float* pe = (const float*)d_in[3];
    const float* W1 = (const float*)d_in[4];
    const float* b1 = (const float*)d_in[5];
    const float* W2 = (const float*)d_in[6];
    const float* b2 = (const float*)d_in[7];
    const float* W3 = (const float*)d_in[8];
    const float* b3 = (const float*)d_in[9];
    const float* Wp = (const float*)d_in[10];
    const float* bp = (const float*)d_in[11];
    float* out = (float*)d_out;

    (void)hipFuncSetAttribute((const void*)infogcn_mfma,
                              hipFuncAttributeMaxDynamicSharedMemorySize, LDS_BYTES);
    infogcn_mfma<<<dim3(NN), dim3(256), LDS_BYTES, stream>>>(
        h, mr, A, pe, W1, b1, W2, b2, W3, b3, Wp, bp, out);
}

// Round 7
// 609.829 us; speedup vs baseline: 3.0032x; 1.2432x over previous
//
#include <hip/hip_runtime.h>

#define NN 64
#define CC 128
#define TT 64
#define VVJ 25
#define FS 28              // zf/fT row stride in floats (112 B, 16B-aligned, 2-way banks)
#define FSLOT 3584         // FS*CC floats per fT ring slot

typedef __attribute__((ext_vector_type(4))) float f4;
typedef __attribute__((ext_vector_type(8))) short bh8;   // 8 bf16 = MFMA frag (4 VGPR)
typedef __attribute__((ext_vector_type(4))) short bh4;   // 4 bf16 = b64 LDS op

// ---- LDS byte offsets ----
// zf : float[128][28]   fp32 z state, [c][v]            14336 B
// fT : float[6][128][28] fp32 f ring, [slot][c][v]      86016 B
// xUh/xUl : bf16 8 KiB each — layout A: [c:128][u:32] (u contig, XOR swz)
//                             layout B (gc3 phase): [v:32][c:128]
// xVh/xVl : bf16 8 KiB each — [v:32][c:128] (c contig, XOR swz)
#define ZF_OFF   0
#define FT_OFF   14336
#define XUH_OFF  100352
#define XUL_OFF  108544
#define XVH_OFF  116736
#define XVL_OFF  124928
#define LDS_BYTES 133120

__device__ __forceinline__ f4 mfma16(bh8 a, bh8 b, f4 c) {
    return __builtin_amdgcn_mfma_f32_16x16x32_bf16(a, b, c, 0, 0, 0);
}

__device__ __forceinline__ float fast_tanh(float x) {
    float e = __expf(2.f * x);
    return 1.f - 2.f / (e + 1.f);
}

struct HL { short h, l; };
__device__ __forceinline__ HL hilo(float x) {
    unsigned xb = __float_as_uint(x);
    HL r;
    r.h = (short)(xb >> 16);
    float l = x - __uint_as_float(xb & 0xffff0000u);
    r.l = (short)(__float_as_uint(l) >> 16);
    return r;
}

__global__ __launch_bounds__(512, 2)
void infogcn_mfma(const float* __restrict__ h, const float* __restrict__ mr,
                  const float* __restrict__ A, const float* __restrict__ pe,
                  const float* __restrict__ W1, const float* __restrict__ b1,
                  const float* __restrict__ W2, const float* __restrict__ b2,
                  const float* __restrict__ W3, const float* __restrict__ b3,
                  const float* __restrict__ Wp, const float* __restrict__ bp,
                  float* __restrict__ out)
{
    extern __shared__ char lds[];
    float* zf = (float*)(lds + ZF_OFF);
    float* fT = (float*)(lds + FT_OFF);
    char* xUh = lds + XUH_OFF;  char* xUl = lds + XUL_OFF;
    char* xVh = lds + XVH_OFF;  char* xVl = lds + XVL_OFF;

    const int tid  = threadIdx.x;
    const int lane = tid & 63;
    const int w    = tid >> 6;       // wave 0..7, 2 per SIMD
    const int col  = lane & 15;
    const int kg   = lane >> 4;      // 0..3
    const int n    = blockIdx.x;
    const float* hn = h   + (size_t)n * 204800;   // CC*TT*VVJ
    float*       on = out + (size_t)n * 204800;

    // ---- launch-state invariance + MFMA zero-padding: zero ALL LDS ----
    for (int i4 = tid; i4 < LDS_BYTES / 4; i4 += 512) ((unsigned*)lds)[i4] = 0u;
    __syncthreads();

    // ================= resident fragments (loop-invariant) =================
    // wmix B-operand = W^T: col o = 16w+col, k c = 32ks + kg*8 + e
    const int o = 16 * w + col;
    bh8 Wh[4][4], Wl[4][4];          // [mat][ks] -> 128 VGPR
    float bias[4];
    {
        const float* Wm[4] = {W1, W2, W3, Wp};
        const float* Bm[4] = {b1, b2, b3, bp};
        #pragma unroll
        for (int mat = 0; mat < 4; ++mat) {
            bias[mat] = Bm[mat][o];
            #pragma unroll
            for (int ks = 0; ks < 4; ++ks) {
                int c0k = 32 * ks + kg * 8;
                #pragma unroll
                for (int e = 0; e < 8; ++e) {
                    HL t = hilo(Wm[mat][o * CC + c0k + e]);
                    Wh[mat][ks][e] = t.h;
                    Wl[mat][ks][e] = t.l;
                }
            }
        }
    }
    // amix B-operand = At (At[u][v] = A[v][u], zero-padded): col v = 16nt+col, k u = kg*8+e
    bh8 Ath[2], Atl[2];
    float asum[2];
    #pragma unroll
    for (int nt = 0; nt < 2; ++nt) {
        int v = 16 * nt + col;
        #pragma unroll
        for (int e = 0; e < 8; ++e) {
            int u = kg * 8 + e;
            float x = (v < VVJ && u < VVJ) ? A[v * VVJ + u] : 0.f;
            HL t = hilo(x);
            Ath[nt][e] = t.h;
            Atl[nt][e] = t.l;
        }
        float s = 0.f;
        if (v < VVJ)
            for (int u = 0; u < VVJ; ++u) s += A[v * VVJ + u];
        asum[nt] = s;
    }

    // ---- out[:, :, 0:6, :] = h[:, :, 0:6, :]  (150 contiguous floats per channel) ----
    for (int idx = tid; idx < 9600; idx += 512) {
        int c = idx / 75, r2 = idx - c * 75;
        *(float2*)&on[c * 1600 + r2 * 2] = *(const float2*)&hn[c * 1600 + r2 * 2];
    }

    // ================= phase lambdas =================
    // amix: P[c][v] = sum_u Z[c][u]*At[u][v] (+ pe_c*Asum_v). A-frag rows c from xU,
    // D rows c0+i / col v = 16nt+col -> xV[v][c0..c0+3] b64.
    auto amix = [&](bool withPE, int t3) {
        int cA = 16 * w + col;
        int bau = (cA * 64 + kg * 16) ^ ((cA & 7) << 4);
        bh8 xh = *(bh8*)(xUh + bau);
        bh8 xl = *(bh8*)(xUl + bau);
        int c0 = 16 * w + kg * 4;
        float pe4[4];
        if (withPE) {
            #pragma unroll
            for (int i = 0; i < 4; ++i) pe4[i] = pe[(c0 + i) * 192 + t3];
        }
        #pragma unroll
        for (int nt = 0; nt < 2; ++nt) {
            f4 acc;
            if (withPE) {
                #pragma unroll
                for (int i = 0; i < 4; ++i) acc[i] = pe4[i] * asum[nt];
            } else {
                acc = (f4){0.f, 0.f, 0.f, 0.f};
            }
            acc = mfma16(xh, Ath[nt], acc);
            acc = mfma16(xh, Atl[nt], acc);
            acc = mfma16(xl, Ath[nt], acc);
            int v = 16 * nt + col;
            bh4 h4, l4;
            #pragma unroll
            for (int i = 0; i < 4; ++i) {
                HL t = hilo(acc[i]);
                h4[i] = t.h;
                l4[i] = t.l;
            }
            int ba = (v * 256 + c0 * 2) ^ ((v & 7) << 4);
            *(bh4*)(xVh + ba) = h4;
            *(bh4*)(xVl + ba) = l4;
        }
    };

    // wmix: Q[v][o] = sum_c X[v][c]*W[o][c]. A-frags (rows v) from a V-layout buffer.
    auto wmix_core = [&](int mat, f4 (&acc)[2], const char* axh, const char* axl) {
        #pragma unroll
        for (int m = 0; m < 2; ++m) {
            int vA = 16 * m + col;
            int sw = (vA & 7) << 4;
            #pragma unroll
            for (int ks = 0; ks < 4; ++ks) {
                int ba = (vA * 256 + ks * 64 + kg * 16) ^ sw;
                bh8 xh = *(bh8*)(axh + ba);
                bh8 xl = *(bh8*)(axl + ba);
                acc[m] = mfma16(xh, Wh[mat][ks], acc[m]);
                acc[m] = mfma16(xh, Wl[mat][ks], acc[m]);
                acc[m] = mfma16(xl, Wh[mat][ks], acc[m]);
            }
        }
    };

    // tanh + hi/lo -> xU U-layout [o][v0..v0+3] b64 (feeds next amix)
    auto gc_store = [&](int mat, const f4 (&acc)[2]) {
        #pragma unroll
        for (int m = 0; m < 2; ++m) {
            int v0 = 16 * m + kg * 4;
            bh4 h4, l4;
            #pragma unroll
            for (int i = 0; i < 4; ++i) {
                float y = fast_tanh(acc[m][i] + bias[mat]);
                HL t = hilo(y);
                h4[i] = t.h;
                l4[i] = t.l;
            }
            int ba = (o * 64 + v0 * 2) ^ ((o & 7) << 4);
            *(bh4*)(xUh + ba) = h4;
            *(bh4*)(xUl + ba) = l4;
        }
    };

    // tanh + hi/lo -> xU buffer in V-layout [v][o] scalar (feeds Wp as A-operand)
    auto gc3_store = [&](const f4 (&acc)[2]) {
        #pragma unroll
        for (int m = 0; m < 2; ++m) {
            #pragma unroll
            for (int i = 0; i < 4; ++i) {
                int v = 16 * m + kg * 4 + i;
                float y = fast_tanh(acc[m][i] + bias[2]);
                HL t = hilo(y);
                int ba = (v * 256 + o * 2) ^ ((v & 7) << 4);
                *(short*)(xUh + ba) = t.h;
                *(short*)(xUl + ba) = t.l;
            }
        }
    };

    // Wp epilogue: fp32 + bias -> fT[slot][o][v], v<25 only
    auto wp_store = [&](const f4 (&acc)[2], int slot) {
        #pragma unroll
        for (int m = 0; m < 2; ++m) {
            #pragma unroll
            for (int i = 0; i < 4; ++i) {
                int v = 16 * m + kg * 4 + i;
                if (v < VVJ)
                    fT[slot * FSLOT + o * FS + v] = acc[m][i] + bias[3];
            }
        }
    };

    auto ode = [&](int t, int slot) {
        // pre: z_t snapshot (bf16 hi/lo) in xU U-layout; barrier done
        amix(true, 3 * t);
        __syncthreads();
        f4 acc[2];
        acc[0] = acc[1] = (f4){0.f, 0.f, 0.f, 0.f};
        wmix_core(0, acc, xVh, xVl);
        gc_store(0, acc);
        __syncthreads();
        amix(false, 0);
        __syncthreads();
        acc[0] = acc[1] = (f4){0.f, 0.f, 0.f, 0.f};
        wmix_core(1, acc, xVh, xVl);
        gc_store(1, acc);
        __syncthreads();
        amix(false, 0);
        __syncthreads();
        acc[0] = acc[1] = (f4){0.f, 0.f, 0.f, 0.f};
        wmix_core(2, acc, xVh, xVl);
        gc3_store(acc);            // xU is dead here (amix3 consumed it pre-barrier)
        __syncthreads();
        acc[0] = acc[1] = (f4){0.f, 0.f, 0.f, 0.f};
        wmix_core(3, acc, xUh, xUl);   // Wp reads gc3's V-layout data from xU
        wp_store(acc, slot);
        __syncthreads();
    };

    // ================= initial 6 odes =================
    #pragma unroll 1
    for (int i = 0; i < 6; ++i) {
        for (int idx = tid; idx < 1024; idx += 512) {
            int vq = idx & 7, c = idx >> 3;
            int v0 = vq * 4;
            int ba = (c * 64 + v0 * 2) ^ ((c & 7) << 4);
            bh4 h4 = (bh4){0,0,0,0}, l4 = (bh4){0,0,0,0};
            if (vq < 7) {
                #pragma unroll
                for (int j = 0; j < 4; ++j) {
                    int v = v0 + j;
                    float z = (v < VVJ) ? hn[c * 1600 + i * 25 + v] : 0.f;
                    HL t = hilo(z);
                    h4[j] = t.h;
                    l4[j] = t.l;
                }
            }
            *(bh4*)(xUh + ba) = h4;
            *(bh4*)(xUl + ba) = l4;
        }
        __syncthreads();
        ode(i, i);
    }

    // ---- z_cand = h[:,:,5,:] into zf [c][v] (pad stays 0) ----
    for (int idx = tid; idx < 1024; idx += 512) {
        int vq = idx & 7, c = idx >> 3;
        if (vq < 7) {
            int v0 = vq * 4;
            #pragma unroll
            for (int j = 0; j < 4; ++j) {
                int v = v0 + j;
                zf[c * FS + v] = (v < VVJ) ? hn[c * 1600 + 125 + v] : 0.f;
            }
        }
    }
    __syncthreads();

    const float coef[6] = { 4277.f/1440.f, -7923.f/1440.f, 9982.f/1440.f,
                            -7298.f/1440.f, 2877.f/1440.f, -475.f/1440.f };
    int head = 5;

    #pragma unroll 1
    for (int t = 5; t < TT - 1; ++t) {
        bool msk = mr[(t - 5) * NN + n] < 0.8f;   // block-uniform
        // fused: z_t select -> bf16 snapshot (xU) ; z_next = z_t + sum coef*f -> zf, out
        for (int idx = tid; idx < 1024; idx += 512) {
            int vq = idx & 7, c = idx >> 3;
            int v0 = vq * 4;
            int ba = (c * 64 + v0 * 2) ^ ((c & 7) << 4);
            if (vq < 7) {
                f4 zt;
                if (msk) {
                    zt = *(const f4*)&zf[c * FS + v0];     // pad lanes read 0
                } else {
                    #pragma unroll
                    for (int j = 0; j < 4; ++j) {
                        int v = v0 + j;
                        zt[j] = (v < VVJ) ? hn[c * 1600 + t * 25 + v] : 0.f;
                    }
                }
                bh4 h4, l4;
                #pragma unroll
                for (int j = 0; j < 4; ++j) {
                    HL tt = hilo(zt[j]);
                    h4[j] = tt.h;
                    l4[j] = tt.l;
                }
                *(bh4*)(xUh + ba) = h4;
                *(bh4*)(xUl + ba) = l4;
                f4 zn = zt;
                #pragma unroll
                for (int k = 0; k < 6; ++k) {
                    int s = head - k; if (s < 0) s += 6;
                    f4 fq = *(const f4*)&fT[s * FSLOT + c * FS + v0];
                    zn += coef[k] * fq;
                }
                *(f4*)&zf[c * FS + v0] = zn;               // pad stays 0 (0 + coef*0)
                #pragma unroll
                for (int j = 0; j < 4; ++j) {
                    int v = v0 + j;
                    if (v < VVJ) on[c * 1600 + (t + 1) * 25 + v] = zn[j];
                }
            } else {
                *(bh4*)(xUh + ba) = (bh4){0,0,0,0};        // keep u=28..31 zero
                *(bh4*)(xUl + ba) = (bh4){0,0,0,0};
            }
        }
        __syncthreads();
        if (t < TT - 2) {                                  // f_62 is never consumed
            int slot = head + 1; if (slot >= 6) slot = 0;
            ode(t, slot);
            head = slot;
        }
    }
}

extern "C" void kernel_launch(void* const* d_in, const int* in_sizes, int n_in,
                              void* d_out, int out_size, void* d_ws, size_t ws_size,
                              hipStream_t stream) {
    const float* h  = (const float*)d_in[0];
    const float* mr = (const float*)d_in[1];
    const float* A  = (const float*)d_in[2];
    const float* pe = (const float*)d_in[3];
    const float* W1 = (const float*)d_in[4];
    const float* b1 = (const float*)d_in[5];
    const float* W2 = (const float*)d_in[6];
    const float* b2 = (const float*)d_in[7];
    const float* W3 = (const float*)d_in[8];
    const float* b3 = (const float*)d_in[9];
    const float* Wp = (const float*)d_in[10];
    const float* bp = (const float*)d_in[11];
    float* out = (float*)d_out;

    (void)hipFuncSetAttribute((const void*)infogcn_mfma,
                              hipFuncAttributeMaxDynamicSharedMemorySize, LDS_BYTES);
    infogcn_mfma<<<dim3(NN), dim3(512), LDS_BYTES, stream>>>(
        h, mr, A, pe, W1, b1, W2, b2, W3, b3, Wp, bp, out);
}

// Round 8
// 528.798 us; speedup vs baseline: 3.4634x; 1.1532x over previous
//
#include <hip/hip_runtime.h>

#define NN 64
#define CC 128
#define TT 64
#define VVJ 25

typedef __attribute__((ext_vector_type(4))) float f4;
typedef __attribute__((ext_vector_type(8))) short bh8;   // 8 bf16 = MFMA frag (4 VGPR)
typedef __attribute__((ext_vector_type(4))) short bh4;   // 4 bf16 = b64 LDS op

// LDS: two double-buffered x tiles, bf16 hi/lo, [v:32][c:128], XOR-swizzled rows.
#define XAH_OFF 0
#define XAL_OFF 8192
#define XBH_OFF 16384
#define XBL_OFF 24576
#define LDS_BYTES 32768

__device__ __forceinline__ f4 mfma16(bh8 a, bh8 b, f4 c) {
    return __builtin_amdgcn_mfma_f32_16x16x32_bf16(a, b, c, 0, 0, 0);
}

__device__ __forceinline__ float fast_tanh(float x) {
    float e = __expf(2.f * x);
    return 1.f - 2.f / (e + 1.f);
}

struct HL { short h, l; };
__device__ __forceinline__ HL hilo(float x) {
    unsigned xb = __float_as_uint(x);
    HL r;
    r.h = (short)(xb >> 16);
    float l = x - __uint_as_float(xb & 0xffff0000u);
    r.l = (short)(__float_as_uint(l) >> 16);
    return r;
}

__global__ __launch_bounds__(512, 2)
void infogcn_reg(const float* __restrict__ h, const float* __restrict__ mr,
                 const float* __restrict__ A, const float* __restrict__ pe,
                 const float* __restrict__ W1, const float* __restrict__ b1,
                 const float* __restrict__ W2, const float* __restrict__ b2,
                 const float* __restrict__ W3, const float* __restrict__ b3,
                 const float* __restrict__ Wp, const float* __restrict__ bp,
                 float* __restrict__ out)
{
    extern __shared__ char lds[];
    char* xah = lds + XAH_OFF;  char* xal = lds + XAL_OFF;
    char* xbh = lds + XBH_OFF;  char* xbl = lds + XBL_OFF;

    const int tid  = threadIdx.x;
    const int lane = tid & 63;
    const int w    = tid >> 6;       // wave 0..7, 2 per SIMD
    const int col  = lane & 15;
    const int kg   = lane >> 4;      // 0..3
    const int n    = blockIdx.x;
    const float* hn = h   + (size_t)n * 204800;   // CC*TT*VVJ
    float*       on = out + (size_t)n * 204800;
    const int o = 16 * w + col;      // this lane's channel (c- and o-domain)

    // launch-state invariance: zero LDS (all cells are also written-before-read each launch)
    for (int i4 = tid; i4 < LDS_BYTES / 4; i4 += 512) ((unsigned*)lds)[i4] = 0u;

    // ================= resident fragments (loop-invariant) =================
    // wmix B-operand = W^T: col o, k c = 32ks + kg*8 + e
    bh8 Wh[4][4], Wl[4][4];
    float bias[4];
    {
        const float* Wm[4] = {W1, W2, W3, Wp};
        const float* Bm[4] = {b1, b2, b3, bp};
        #pragma unroll
        for (int mat = 0; mat < 4; ++mat) {
            bias[mat] = Bm[mat][o];
            #pragma unroll
            for (int ks = 0; ks < 4; ++ks) {
                int c0k = 32 * ks + kg * 8;
                #pragma unroll
                for (int e = 0; e < 8; ++e) {
                    HL p = hilo(Wm[mat][o * CC + c0k + e]);
                    Wh[mat][ks][e] = p.h;
                    Wl[mat][ks][e] = p.l;
                }
            }
        }
    }
    // amix B-operand = At (At[u][v] = A[v][u], zero-padded): col v = 16nt+col, k u = kg*8+e
    bh8 Ath[2], Atl[2];
    float asum[2];
    #pragma unroll
    for (int nt = 0; nt < 2; ++nt) {
        int v = 16 * nt + col;
        #pragma unroll
        for (int e = 0; e < 8; ++e) {
            int u = kg * 8 + e;
            float x = (v < VVJ && u < VVJ) ? A[v * VVJ + u] : 0.f;
            HL p = hilo(x);
            Ath[nt][e] = p.h;
            Atl[nt][e] = p.l;
        }
        float s = 0.f;
        if (v < VVJ)
            for (int u = 0; u < VVJ; ++u) s += A[v * VVJ + u];
        asum[nt] = s;
    }

    // out[:, :, 0:6, :] = h[:, :, 0:6, :]
    for (int idx = tid; idx < 9600; idx += 512) {
        int c = idx / 75, r2 = idx - c * 75;
        *(float2*)&on[c * 1600 + r2 * 2] = *(const float2*)&hn[c * 1600 + r2 * 2];
    }
    __syncthreads();   // zero-init visible before first amix writes

    // ================= lambdas =================
    // amix: P[c][v] = sum_u z[c][u]*At[u][v] (+ pe_c*asum_v); z from in-register frag.
    // D rows c = 16w+4kg+i, col v = 16nt+col -> dst[v][c0..c0+3] b64 (hi/lo).
    auto amix_store = [&](bh8 zh, bh8 zl, bool withPE, int t3, char* dh, char* dl) {
        int c0 = 16 * w + kg * 4;
        float pe4[4];
        if (withPE) {
            #pragma unroll
            for (int i = 0; i < 4; ++i) pe4[i] = pe[(c0 + i) * 192 + t3];
        }
        #pragma unroll
        for (int nt = 0; nt < 2; ++nt) {
            f4 acc;
            if (withPE) {
                #pragma unroll
                for (int i = 0; i < 4; ++i) acc[i] = pe4[i] * asum[nt];
            } else {
                acc = (f4){0.f, 0.f, 0.f, 0.f};
            }
            acc = mfma16(zh, Ath[nt], acc);
            acc = mfma16(zh, Atl[nt], acc);
            acc = mfma16(zl, Ath[nt], acc);
            int v = 16 * nt + col;
            bh4 h4, l4;
            #pragma unroll
            for (int i = 0; i < 4; ++i) {
                HL p = hilo(acc[i]);
                h4[i] = p.h;
                l4[i] = p.l;
            }
            int ba = (v * 256 + c0 * 2) ^ ((v & 7) << 4);
            *(bh4*)(dh + ba) = h4;
            *(bh4*)(dl + ba) = l4;
        }
    };

    // wmix: Q[v][o] = sum_c X[v][c]*W[o][c]; A-frags from an LDS x tile.
    auto wmix_core = [&](int mat, f4 (&acc)[2], const char* axh, const char* axl) {
        #pragma unroll
        for (int m = 0; m < 2; ++m) {
            int vA = 16 * m + col;
            int sw = (vA & 7) << 4;
            #pragma unroll
            for (int ks = 0; ks < 4; ++ks) {
                int ba = (vA * 256 + ks * 64 + kg * 16) ^ sw;
                bh8 xh = *(bh8*)(axh + ba);
                bh8 xl = *(bh8*)(axl + ba);
                acc[m] = mfma16(xh, Wh[mat][ks], acc[m]);
                acc[m] = mfma16(xh, Wl[mat][ks], acc[m]);
                acc[m] = mfma16(xl, Wh[mat][ks], acc[m]);
            }
        }
    };

    // D-layout y[v=16m+4kg+i][c=o] -> A-frag [c=o][u=8kg+e] via in-wave kg-permute.
    // src value for (u=8KG+e): m_src=KG>>1, kg_src=((KG&1)<<1)+(e>>2), i_src=e&3.
    auto to_frag = [&](const f4 (&y)[2], bh8& fh, bh8& fl) {
        #pragma unroll
        for (int e = 0; e < 8; ++e) {
            int src = ((((kg & 1) << 1) + (e >> 2)) << 4) + col;
            float t0 = __shfl(y[0][e & 3], src);
            float t1 = __shfl(y[1][e & 3], src);
            float v = (kg < 2) ? t0 : t1;
            HL p = hilo(v);
            fh[e] = p.h;
            fl[e] = p.l;
        }
    };

    // layer-3 output -> LDS in [v][o] layout (A-operand for Wp), scalar b16 stores
    auto gc3_store = [&](const f4 (&acc)[2], char* dh, char* dl) {
        #pragma unroll
        for (int m = 0; m < 2; ++m)
            #pragma unroll
            for (int i = 0; i < 4; ++i) {
                int v = 16 * m + 4 * kg + i;
                float y = fast_tanh(acc[m][i] + bias[2]);
                HL p = hilo(y);
                int ba = (v * 256 + o * 2) ^ ((v & 7) << 4);
                *(short*)(dh + ba) = p.h;
                *(short*)(dl + ba) = p.l;
            }
    };

    // one ODE eval: z frag (in-register) -> f (in-register, D-layout). 4 barriers.
    auto ode = [&](bh8 zh, bh8 zl, int t3, f4 (&fout)[2]) {
        amix_store(zh, zl, true, t3, xah, xal);       // -> xVa
        __syncthreads();
        f4 acc[2];
        acc[0] = acc[1] = (f4){0.f, 0.f, 0.f, 0.f};
        wmix_core(0, acc, xah, xal);
        {
            f4 y[2];
            #pragma unroll
            for (int m = 0; m < 2; ++m)
                #pragma unroll
                for (int i = 0; i < 4; ++i) y[m][i] = fast_tanh(acc[m][i] + bias[0]);
            bh8 yh, yl;
            to_frag(y, yh, yl);
            amix_store(yh, yl, false, 0, xbh, xbl);   // -> xVb
        }
        __syncthreads();
        acc[0] = acc[1] = (f4){0.f, 0.f, 0.f, 0.f};
        wmix_core(1, acc, xbh, xbl);
        {
            f4 y[2];
            #pragma unroll
            for (int m = 0; m < 2; ++m)
                #pragma unroll
                for (int i = 0; i < 4; ++i) y[m][i] = fast_tanh(acc[m][i] + bias[1]);
            bh8 yh, yl;
            to_frag(y, yh, yl);
            amix_store(yh, yl, false, 0, xah, xal);   // -> xVa (wmix1 readers passed B2)
        }
        __syncthreads();
        acc[0] = acc[1] = (f4){0.f, 0.f, 0.f, 0.f};
        wmix_core(2, acc, xah, xal);
        gc3_store(acc, xbh, xbl);                     // -> xVb (wmix2 readers passed B3)
        __syncthreads();
        acc[0] = acc[1] = (f4){0.f, 0.f, 0.f, 0.f};
        wmix_core(3, acc, xbh, xbl);                  // Wp
        fout[0] = acc[0] + bias[3];
        fout[1] = acc[1] + bias[3];
    };

    // ================= initial 6 odes: f ring fully in registers =================
    f4 fr[6][2];   // fr[k] = f_{(t-1)-k} at loop head; D-layout [v=16m+4kg+i][c=o]
    #pragma unroll
    for (int i = 0; i < 6; ++i) {
        bh8 zh, zl;
        #pragma unroll
        for (int e = 0; e < 8; ++e) {
            int u = 8 * kg + e;
            float zv = (u < VVJ) ? hn[o * 1600 + i * 25 + u] : 0.f;
            HL p = hilo(zv);
            zh[e] = p.h;
            zl[e] = p.l;
        }
        ode(zh, zl, 3 * i, fr[5 - i]);   // fr[k] = f_{5-k}
    }

    // z_cand = h[:,:,5,:] in D-layout registers
    f4 zm[2];
    #pragma unroll
    for (int m = 0; m < 2; ++m)
        #pragma unroll
        for (int i = 0; i < 4; ++i) {
            int v = 16 * m + 4 * kg + i;
            zm[m][i] = (v < VVJ) ? hn[o * 1600 + 125 + v] : 0.f;
        }

    const float coef[6] = { 4277.f/1440.f, -7923.f/1440.f, 9982.f/1440.f,
                            -7298.f/1440.f, 2877.f/1440.f, -475.f/1440.f };

    #pragma unroll 1
    for (int t = 5; t < TT - 1; ++t) {
        bool msk = mr[(t - 5) * NN + n] < 0.8f;   // block-uniform
        f4 zt[2];
        if (msk) {
            zt[0] = zm[0]; zt[1] = zm[1];
        } else {
            #pragma unroll
            for (int m = 0; m < 2; ++m)
                #pragma unroll
                for (int i = 0; i < 4; ++i) {
                    int v = 16 * m + 4 * kg + i;
                    zt[m][i] = (v < VVJ) ? hn[o * 1600 + t * 25 + v] : 0.f;
                }
        }
        // z_t snapshot -> A-frag (in-register, no barrier)
        bh8 zh, zl;
        to_frag(zt, zh, zl);
        // z_next = z_t + sum_k coef[k] * fr[k]  (pure register FMAs)
        f4 zn[2];
        #pragma unroll
        for (int m = 0; m < 2; ++m) {
            zn[m] = zt[m];
            #pragma unroll
            for (int k = 0; k < 6; ++k) zn[m] += coef[k] * fr[k][m];
        }
        // out[:, :, t+1, :]
        #pragma unroll
        for (int m = 0; m < 2; ++m)
            #pragma unroll
            for (int i = 0; i < 4; ++i) {
                int v = 16 * m + 4 * kg + i;
                if (v < VVJ) on[o * 1600 + (t + 1) * 25 + v] = zn[m][i];
            }
        zm[0] = zn[0]; zm[1] = zn[1];

        if (t < TT - 2) {                         // f_62 never consumed
            f4 fnew[2];
            ode(zh, zl, 3 * t, fnew);
            #pragma unroll
            for (int k = 5; k > 0; --k) { fr[k][0] = fr[k-1][0]; fr[k][1] = fr[k-1][1]; }
            fr[0][0] = fnew[0]; fr[0][1] = fnew[1];
        }
    }
}

extern "C" void kernel_launch(void* const* d_in, const int* in_sizes, int n_in,
                              void* d_out, int out_size, void* d_ws, size_t ws_size,
                              hipStream_t stream) {
    const float* h  = (const float*)d_in[0];
    const float* mr = (const float*)d_in[1];
    const float* A  = (const float*)d_in[2];
    const float* pe = (const float*)d_in[3];
    const float* W1 = (const float*)d_in[4];
    const float* b1 = (const float*)d_in[5];
    const float* W2 = (const float*)d_in[6];
    const float* b2 = (const float*)d_in[7];
    const float* W3 = (const float*)d_in[8];
    const float* b3 = (const float*)d_in[9];
    const float* Wp = (const float*)d_in[10];
    const float* bp = (const float*)d_in[11];
    float* out = (float*)d_out;

    (void)hipFuncSetAttribute((const void*)infogcn_reg,
                              hipFuncAttributeMaxDynamicSharedMemorySize, LDS_BYTES);
    infogcn_reg<<<dim3(NN), dim3(512), LDS_BYTES, stream>>>(
        h, mr, A, pe, W1, b1, W2, b2, W3, b3, Wp, bp, out);
}